// Round 2
// baseline (314.085 us; speedup 1.0000x reference)
//
#include <hip/hip_runtime.h>

typedef __bf16 bf16_t;
typedef __bf16 bf16x8 __attribute__((ext_vector_type(8)));
typedef float f32x4 __attribute__((ext_vector_type(4)));

#define MFMA_16x16x32(a, b, c) __builtin_amdgcn_mfma_f32_16x16x32_bf16((a), (b), (c), 0, 0, 0)

__device__ inline bf16x8 cvt8(const float* __restrict__ p) {
  bf16x8 r;
#pragma unroll
  for (int j = 0; j < 8; j++) r[j] = (bf16_t)p[j];
  return r;
}

// async 16B global->LDS DMA: LDS dest = (wave-uniform) base + lane*16B
__device__ inline void load_lds16(const bf16_t* g, bf16_t* l) {
  __builtin_amdgcn_global_load_lds(
      (const __attribute__((address_space(1))) void*)g,
      (__attribute__((address_space(3))) void*)l, 16, 0, 0);
}

// ---------------------------------------------------------------------------
// fp32 -> bf16 convert for x (16777216), qkv_w (786432), proj_w (262144)
// ---------------------------------------------------------------------------
__global__ __launch_bounds__(256) void convert_k(
    const float* __restrict__ x, const float* __restrict__ qkv_w,
    const float* __restrict__ proj_w,
    bf16_t* __restrict__ xbf, bf16_t* __restrict__ wqkvbf,
    bf16_t* __restrict__ wprojbf) {
  size_t base = ((size_t)blockIdx.x * 256 + threadIdx.x) * 8;
  if (base < 16777216) {
    *(bf16x8*)(xbf + base) = cvt8(x + base);
  } else if (base < 17563648) {
    size_t o = base - 16777216;
    *(bf16x8*)(wqkvbf + o) = cvt8(qkv_w + o);
  } else {
    size_t o = base - 17563648;
    *(bf16x8*)(wprojbf + o) = cvt8(proj_w + o);
  }
}

// ---------------------------------------------------------------------------
// bias gather into C-fragment-major layout (fp32)
// ---------------------------------------------------------------------------
__global__ __launch_bounds__(256) void bias_gather_k(
    const float* __restrict__ table, const int* __restrict__ rel,
    float* __restrict__ biasws) {
  int idx = blockIdx.x * 256 + threadIdx.x;  // 0 .. 1048576
  int h = idx >> 16;
  int rem = idx & 65535;
  int rb = rem >> 12;
  int ct = (rem >> 8) & 15;
  int L = (rem >> 2) & 63;
  int r = idx & 3;
  int row = rb * 16 + (L >> 4) * 4 + r;
  int col = ct * 16 + (L & 15);
  biasws[idx] = table[rel[row * 256 + col] * 16 + h];
}

// ---------------------------------------------------------------------------
// 256x256-tile 8-phase GEMM core with persistent tile-chaining.
// 8 waves (2M x 4N), per-wave 128x64 output = acc[8][4].
// LDS 128 KiB (A,B K-tiles double-buffered, BK=64). XOR swizzle slot^=row&7
// on pre-swizzled global source + ds_read address. Counted vmcnt(4) gates,
// draining to 0 only at the very last K-tile of the chain.
// Quadrant order lolo -> hilo -> hihi -> lohi: ds_reads 12/8/4/0 per phase,
// peak frag liveness 80 VGPR (fbl dies after ph2, fah after ph3).
// ---------------------------------------------------------------------------
#define PH_MID()                                          \
  do {                                                    \
    __builtin_amdgcn_s_barrier();                         \
    asm volatile("s_waitcnt lgkmcnt(0)" ::: "memory");    \
    __builtin_amdgcn_sched_barrier(0);                    \
    __builtin_amdgcn_s_setprio(1);                        \
  } while (0)

#define PH_END()                                          \
  do {                                                    \
    __builtin_amdgcn_s_setprio(0);                        \
    __builtin_amdgcn_s_barrier();                         \
    __builtin_amdgcn_sched_barrier(0);                    \
  } while (0)

// stage 2 of the 4 chunks of tile g's A (rows c*64.., c*64+64..) into buf
#define STG_A2(buf, g, c)                                                        \
  do {                                                                           \
    load_lds16(ga + ((g)&7) * 64 + (c)*32768, la + (buf)*16384 + (c)*4096);      \
    load_lds16(ga + ((g)&7) * 64 + ((c) + 1) * 32768,                            \
               la + (buf)*16384 + ((c) + 1) * 4096);                             \
  } while (0)
#define STG_B2(buf, g, c)                                                        \
  do {                                                                           \
    load_lds16(gb + ((g) >> 3) * 131072 + ((g)&7) * 64 + (c)*32768,              \
               lb + (buf)*16384 + (c)*4096);                                     \
    load_lds16(gb + ((g) >> 3) * 131072 + ((g)&7) * 64 + ((c) + 1) * 32768,      \
               lb + (buf)*16384 + ((c) + 1) * 4096);                             \
  } while (0)

#define RDA(dst, buf, ibase)                                                     \
  _Pragma("unroll") for (int i = 0; i < 4; ++i) {                                \
    dst[i][0] = *(const bf16x8*)&As[(buf)*16384 + a0 + ((ibase) + i) * 1024];    \
    dst[i][1] = *(const bf16x8*)&As[(buf)*16384 + a1 + ((ibase) + i) * 1024];    \
  }
#define RDB(dst, buf, jbase)                                                     \
  _Pragma("unroll") for (int j = 0; j < 2; ++j) {                                \
    dst[j][0] = *(const bf16x8*)&Bs[(buf)*16384 + b0 + ((jbase) + j) * 1024];    \
    dst[j][1] = *(const bf16x8*)&Bs[(buf)*16384 + b1 + ((jbase) + j) * 1024];    \
  }

#define MFQ(Af, Bf, I0, J0)                                                      \
  _Pragma("unroll") for (int i = 0; i < 4; ++i) _Pragma("unroll")                \
      for (int j = 0; j < 2; ++j) {                                              \
    acc[(I0) + i][(J0) + j] =                                                    \
        MFMA_16x16x32(Af[i][0], Bf[j][0], acc[(I0) + i][(J0) + j]);              \
    acc[(I0) + i][(J0) + j] =                                                    \
        MFMA_16x16x32(Af[i][1], Bf[j][1], acc[(I0) + i][(J0) + j]);              \
  }

// one group = 2 K-tiles (2G -> buf0, 2G+1 -> buf1), 8 phases.
// Steady-state staging: B of t+1 during phases 1-2, A of t+2 during 3-4, etc.
#define GROUP(G, NT)                                                             \
  do {                                                                           \
    {                                                                            \
      bf16x8 fal[4][2], fbl[2][2], fah[4][2], fbh[2][2];                         \
      RDA(fal, 0, 0); RDB(fbl, 0, 0);                                            \
      if ((2 * (G) + 1) < (NT)) STG_B2(1, 2 * (G) + 1, 0);                       \
      PH_MID(); MFQ(fal, fbl, 0, 0); PH_END();                                   \
      RDA(fah, 0, 4);                                                            \
      if ((2 * (G) + 1) < (NT)) STG_B2(1, 2 * (G) + 1, 2);                       \
      PH_MID(); MFQ(fah, fbl, 4, 0); PH_END();                                   \
      RDB(fbh, 0, 2);                                                            \
      if ((2 * (G) + 2) < (NT)) STG_A2(0, 2 * (G) + 2, 0);                       \
      PH_MID(); MFQ(fah, fbh, 4, 2); PH_END();                                   \
      if ((2 * (G) + 2) < (NT)) STG_A2(0, 2 * (G) + 2, 2);                       \
      PH_MID(); MFQ(fal, fbh, 0, 2);                                             \
      __builtin_amdgcn_s_setprio(0);                                             \
      if ((2 * (G) + 2) < (NT))                                                  \
        asm volatile("s_waitcnt vmcnt(4)" ::: "memory");                         \
      else                                                                       \
        asm volatile("s_waitcnt vmcnt(0)" ::: "memory");                         \
      __builtin_amdgcn_s_barrier();                                              \
      __builtin_amdgcn_sched_barrier(0);                                         \
    }                                                                            \
    {                                                                            \
      bf16x8 fal[4][2], fbl[2][2], fah[4][2], fbh[2][2];                         \
      RDA(fal, 1, 0); RDB(fbl, 1, 0);                                            \
      if ((2 * (G) + 2) < (NT)) STG_B2(0, 2 * (G) + 2, 0);                       \
      PH_MID(); MFQ(fal, fbl, 0, 0); PH_END();                                   \
      RDA(fah, 1, 4);                                                            \
      if ((2 * (G) + 2) < (NT)) STG_B2(0, 2 * (G) + 2, 2);                       \
      PH_MID(); MFQ(fah, fbl, 4, 0); PH_END();                                   \
      RDB(fbh, 1, 2);                                                            \
      if ((2 * (G) + 3) < (NT)) STG_A2(1, 2 * (G) + 3, 0);                       \
      PH_MID(); MFQ(fah, fbh, 4, 2); PH_END();                                   \
      if ((2 * (G) + 3) < (NT)) STG_A2(1, 2 * (G) + 3, 2);                       \
      PH_MID(); MFQ(fal, fbh, 0, 2);                                             \
      __builtin_amdgcn_s_setprio(0);                                             \
      if ((2 * (G) + 3) < (NT))                                                  \
        asm volatile("s_waitcnt vmcnt(4)" ::: "memory");                         \
      else                                                                       \
        asm volatile("s_waitcnt vmcnt(0)" ::: "memory");                         \
      __builtin_amdgcn_s_barrier();                                              \
      __builtin_amdgcn_sched_barrier(0);                                         \
    }                                                                            \
  } while (0)

// common per-thread geometry setup (names used by the macros)
#define GEMM_SETUP(Ap, Wp)                                                       \
  __shared__ bf16_t As[2 * 16384];                                               \
  __shared__ bf16_t Bs[2 * 16384];                                               \
  const int t = threadIdx.x;                                                     \
  const int w = t >> 6, L = t & 63;                                              \
  const int wm = w >> 2, wn = w & 3;                                             \
  const int lrow = L & 15, lq = L >> 4;                                          \
  const int srow = t >> 3;                                                       \
  const int sslot = (t & 7) ^ (srow & 7);                                        \
  const bf16_t* ga = (Ap) + (size_t)(m0 + srow) * 512 + sslot * 8;               \
  const bf16_t* gb = (Wp) + (size_t)(n0 + srow) * 512 + sslot * 8;               \
  bf16_t* la = As + t * 8;                                                       \
  bf16_t* lb = Bs + t * 8;                                                       \
  const int m8 = (lrow & 7) * 8;                                                 \
  const int a0 = (wm * 128 + lrow) * 64 + ((lq * 8) ^ m8);                       \
  const int a1 = (wm * 128 + lrow) * 64 + ((32 + lq * 8) ^ m8);                  \
  const int b0 = (wn * 64 + lrow) * 64 + ((lq * 8) ^ m8);                        \
  const int b1 = (wn * 64 + lrow) * 64 + ((32 + lq * 8) ^ m8);

#define PROLOGUE()                                                               \
  STG_A2(0, 0, 0); STG_A2(0, 0, 2);                                              \
  STG_B2(0, 0, 0); STG_B2(0, 0, 2);                                              \
  STG_A2(1, 1, 0); STG_A2(1, 1, 2);                                              \
  asm volatile("s_waitcnt vmcnt(4)" ::: "memory");                               \
  __builtin_amdgcn_s_barrier();                                                  \
  __builtin_amdgcn_sched_barrier(0);

// ---------------------------------------------------------------------------
// QKV GEMM: 256 blocks (1/CU), each chains 3 nt-tiles of one mt
// (24 K-tiles, one continuous pipeline; epilogues overlap in-flight staging).
// ---------------------------------------------------------------------------
__global__ __launch_bounds__(512, 2) void qkv_gemm256_k(
    const bf16_t* __restrict__ A, const bf16_t* __restrict__ W,
    const float* __restrict__ Bvec,
    bf16_t* __restrict__ qws, bf16_t* __restrict__ kws, bf16_t* __restrict__ vws) {
  const int id = blockIdx.x;                  // 0..255
  const int lin = (id & 7) * 32 + (id >> 3);  // bijective XCD swizzle
  const int mt = lin >> 1;
  const int ntb = (lin & 1) * 3;              // nt = ntb..ntb+2
  const int m0 = mt * 256;
  const int n0 = ntb * 256;

  GEMM_SETUP(A, W);

  // hoist bias for all 3 output tiles; fold into accumulator init
  float bias_r[3][4];
#pragma unroll
  for (int ot = 0; ot < 3; ++ot) {
    int c0 = (ntb + ot) * 256 + wn * 64;
#pragma unroll
    for (int jj = 0; jj < 4; ++jj) bias_r[ot][jj] = Bvec[c0 + jj * 16 + lrow];
  }

  f32x4 acc[8][4];
#pragma unroll
  for (int i = 0; i < 8; ++i)
#pragma unroll
    for (int jj = 0; jj < 4; ++jj) {
      float bv = bias_r[0][jj];
      acc[i][jj] = (f32x4){bv, bv, bv, bv};
    }

  PROLOGUE();

#pragma unroll
  for (int G = 0; G < 12; ++G) {
    GROUP(G, 24);
    if ((G & 3) == 3) {
      const int ot = G >> 2;  // 0,1,2 (compile-time after unroll)
      const int col0 = (ntb + ot) * 256 + wn * 64;  // 64-aligned
      const int s = col0 >> 9;
      bf16_t* dst = (s == 0) ? qws : (s == 1) ? kws : vws;
      const float mul = (s == 0) ? 0.17677669529663687f : 1.0f;
#pragma unroll
      for (int jj = 0; jj < 4; ++jj) {
        int o = col0 + jj * 16 + lrow;
        int rem = o & 511;
        int hh = rem >> 5, d = rem & 31;
#pragma unroll
        for (int i = 0; i < 8; ++i) {
#pragma unroll
          for (int r = 0; r < 4; ++r) {
            int m = m0 + wm * 128 + i * 16 + lq * 4 + r;
            int b = m >> 8, n = m & 255;
            dst[(size_t)(((b * 16 + hh) * 256 + n) << 5) + d] =
                (bf16_t)(acc[i][jj][r] * mul);
          }
        }
      }
      if (ot < 2) {
#pragma unroll
        for (int i = 0; i < 8; ++i)
#pragma unroll
          for (int jj = 0; jj < 4; ++jj) {
            float bv = bias_r[ot + 1][jj];
            acc[i][jj] = (f32x4){bv, bv, bv, bv};
          }
      }
    }
  }
}

// ---------------------------------------------------------------------------
// Proj GEMM 256x256: 128 mt x 2 nt = 256 blocks (1 tile each, 8 K-tiles).
// ---------------------------------------------------------------------------
__global__ __launch_bounds__(512, 2) void proj_gemm256_k(
    const bf16_t* __restrict__ A, const bf16_t* __restrict__ W,
    const float* __restrict__ Bvec, float* __restrict__ out) {
  const int id = blockIdx.x;                  // 0..255
  const int lin = (id & 7) * 32 + (id >> 3);
  const int mt = lin >> 1, nt = lin & 1;
  const int m0 = mt * 256, n0 = nt * 256;

  GEMM_SETUP(A, W);

  float bias_r[4];
#pragma unroll
  for (int jj = 0; jj < 4; ++jj)
    bias_r[jj] = Bvec[n0 + wn * 64 + jj * 16 + lrow];

  f32x4 acc[8][4];
#pragma unroll
  for (int i = 0; i < 8; ++i)
#pragma unroll
    for (int jj = 0; jj < 4; ++jj) {
      float bv = bias_r[jj];
      acc[i][jj] = (f32x4){bv, bv, bv, bv};
    }

  PROLOGUE();

#pragma unroll
  for (int G = 0; G < 4; ++G) GROUP(G, 8);

#pragma unroll
  for (int jj = 0; jj < 4; ++jj) {
    int o = n0 + wn * 64 + jj * 16 + lrow;
#pragma unroll
    for (int i = 0; i < 8; ++i) {
#pragma unroll
      for (int r = 0; r < 4; ++r) {
        int m = m0 + wm * 128 + i * 16 + lq * 4 + r;
        out[(size_t)m * 512 + o] = acc[i][jj][r];
      }
    }
  }
}

// ---------------------------------------------------------------------------
// Attention: one block per (b, h, 64-row strip), XCD-swizzled.
// ---------------------------------------------------------------------------
__global__ __launch_bounds__(256) void attn_k(
    const bf16_t* __restrict__ qws, const bf16_t* __restrict__ kws,
    const bf16_t* __restrict__ vws, const float* __restrict__ biasws,
    bf16_t* __restrict__ aows) {
  __shared__ __align__(16) char smem[33792 + 16896];
  bf16_t* Ps = (bf16_t*)smem;            // 4 waves x [16][264]
  bf16_t* Vs = (bf16_t*)(smem + 33792);  // [32][264] transposed V

  const int id = blockIdx.x;             // 0..8191
  const int xcd = id & 7;
  const int jj = id >> 3;                // 0..1023
  const int bh = (jj >> 2) * 8 + xcd;    // 0..2047
  const int strip = jj & 3;
  const int h = bh & 15, b = bh >> 4;

  const int t = threadIdx.x;
  const int w = t >> 6, L = t & 63;
  const int lrow = L & 15, lq = L >> 4;

  const bf16_t* kbase = kws + (size_t)bh * 8192;
  const bf16_t* vbase = vws + (size_t)bh * 8192;
#pragma unroll
  for (int c = 0; c < 4; c++) {
    bf16x8 vv = *(const bf16x8*)(vbase + t * 32 + c * 8);
#pragma unroll
    for (int j = 0; j < 8; j++) Vs[(c * 8 + j) * 264 + t] = vv[j];
  }

  const bf16_t* qbase = qws + (size_t)bh * 8192 + (strip * 64 + w * 16) * 32;
  bf16x8 qf = *(const bf16x8*)(qbase + lrow * 32 + lq * 8);
  bf16x8 kf[16];
#pragma unroll
  for (int ct = 0; ct < 16; ct++)
    kf[ct] = *(const bf16x8*)(kbase + (ct * 16 + lrow) * 32 + lq * 8);

  const float* bb = biasws + h * 65536 + (strip * 4 + w) * 4096;
  f32x4 S[16];
#pragma unroll
  for (int ct = 0; ct < 16; ct++) {
    f32x4 bi = *(const f32x4*)(bb + ct * 256 + L * 4);
    S[ct] = MFMA_16x16x32(qf, kf[ct], bi);
  }

  float sm[4] = {0.f, 0.f, 0.f, 0.f};
#pragma unroll
  for (int ct = 0; ct < 16; ct++)
#pragma unroll
    for (int r = 0; r < 4; r++) {
      float e = __expf(S[ct][r]);
      S[ct][r] = e;
      sm[r] += e;
    }
#pragma unroll
  for (int r = 0; r < 4; r++)
#pragma unroll
    for (int msk = 1; msk < 16; msk <<= 1)
      sm[r] += __shfl_xor(sm[r], msk, 64);
  float inv[4];
#pragma unroll
  for (int r = 0; r < 4; r++) inv[r] = 1.0f / sm[r];

  bf16_t* Pw = Ps + w * 4224;
#pragma unroll
  for (int ct = 0; ct < 16; ct++)
#pragma unroll
    for (int r = 0; r < 4; r++)
      Pw[(lq * 4 + r) * 264 + ct * 16 + lrow] = (bf16_t)S[ct][r];

  __syncthreads();  // Vs writes visible to all waves

  f32x4 O0 = {}, O1 = {};
#pragma unroll
  for (int c = 0; c < 8; c++) {
    bf16x8 pf = *(const bf16x8*)&Pw[lrow * 264 + c * 32 + lq * 8];
    bf16x8 v0 = *(const bf16x8*)&Vs[lrow * 264 + c * 32 + lq * 8];
    bf16x8 v1 = *(const bf16x8*)&Vs[(16 + lrow) * 264 + c * 32 + lq * 8];
    O0 = MFMA_16x16x32(pf, v0, O0);
    O1 = MFMA_16x16x32(pf, v1, O1);
  }
  bf16_t* obase = aows + (size_t)(b * 256 + strip * 64 + w * 16) * 512 + h * 32;
#pragma unroll
  for (int r = 0; r < 4; r++) {
    int rl = lq * 4 + r;
    obase[rl * 512 + lrow] = (bf16_t)(O0[r] * inv[r]);
    obase[rl * 512 + 16 + lrow] = (bf16_t)(O1[r] * inv[r]);
  }
}

// ---------------------------------------------------------------------------
extern "C" void kernel_launch(void* const* d_in, const int* in_sizes, int n_in,
                              void* d_out, int out_size, void* d_ws, size_t ws_size,
                              hipStream_t stream) {
  (void)in_sizes; (void)n_in; (void)out_size; (void)ws_size;
  const float* x      = (const float*)d_in[0];
  const float* qkv_w  = (const float*)d_in[1];
  const float* qkv_b  = (const float*)d_in[2];
  const float* proj_w = (const float*)d_in[3];
  const float* proj_b = (const float*)d_in[4];
  const float* table  = (const float*)d_in[5];
  const int*   rel    = (const int*)d_in[6];

  const size_t QKV_ELEMS = 16777216;  // 128*16*256*32
  bf16_t* qws     = (bf16_t*)d_ws;
  bf16_t* kws     = qws + QKV_ELEMS;
  bf16_t* vws     = kws + QKV_ELEMS;
  float*  biasws  = (float*)(vws + QKV_ELEMS);
  bf16_t* wqkvbf  = (bf16_t*)(biasws + 1048576);
  bf16_t* wprojbf = wqkvbf + 786432;
  bf16_t* xbf     = wprojbf + 262144;  // aliased with aows (liveness disjoint)
  bf16_t* aows    = xbf;
  float*  out     = (float*)d_out;

  convert_k<<<8704, 256, 0, stream>>>(x, qkv_w, proj_w, xbf, wqkvbf, wprojbf);
  bias_gather_k<<<4096, 256, 0, stream>>>(table, rel, biasws);
  qkv_gemm256_k<<<256, 512, 0, stream>>>(xbf, wqkvbf, qkv_b, qws, kws, vws);
  attn_k<<<8192, 256, 0, stream>>>(qws, kws, vws, biasws, aows);
  proj_gemm256_k<<<256, 512, 0, stream>>>(aows, wprojbf, proj_b, out);
}

// Round 4
// 288.388 us; speedup vs baseline: 1.0891x; 1.0891x over previous
//
#include <hip/hip_runtime.h>

typedef __bf16 bf16_t;
typedef __bf16 bf16x8 __attribute__((ext_vector_type(8)));
typedef float f32x4 __attribute__((ext_vector_type(4)));

#define MFMA_16x16x32(a, b, c) __builtin_amdgcn_mfma_f32_16x16x32_bf16((a), (b), (c), 0, 0, 0)

__device__ inline bf16x8 cvt8(const float* __restrict__ p) {
  bf16x8 r;
#pragma unroll
  for (int j = 0; j < 8; j++) r[j] = (bf16_t)p[j];
  return r;
}

// async 16B global->LDS DMA: LDS dest = (wave-uniform) base + lane*16B
__device__ inline void load_lds16(const bf16_t* g, bf16_t* l) {
  __builtin_amdgcn_global_load_lds(
      (const __attribute__((address_space(1))) void*)g,
      (__attribute__((address_space(3))) void*)l, 16, 0, 0);
}

// ---------------------------------------------------------------------------
// fp32 -> bf16 convert for x (16777216), qkv_w (786432), proj_w (262144)
// ---------------------------------------------------------------------------
__global__ __launch_bounds__(256) void convert_k(
    const float* __restrict__ x, const float* __restrict__ qkv_w,
    const float* __restrict__ proj_w,
    bf16_t* __restrict__ xbf, bf16_t* __restrict__ wqkvbf,
    bf16_t* __restrict__ wprojbf) {
  size_t base = ((size_t)blockIdx.x * 256 + threadIdx.x) * 8;
  if (base < 16777216) {
    *(bf16x8*)(xbf + base) = cvt8(x + base);
  } else if (base < 17563648) {
    size_t o = base - 16777216;
    *(bf16x8*)(wqkvbf + o) = cvt8(qkv_w + o);
  } else {
    size_t o = base - 17563648;
    *(bf16x8*)(wprojbf + o) = cvt8(proj_w + o);
  }
}

// ---------------------------------------------------------------------------
// bias gather into C-fragment-major layout (fp32)
// ---------------------------------------------------------------------------
__global__ __launch_bounds__(256) void bias_gather_k(
    const float* __restrict__ table, const int* __restrict__ rel,
    float* __restrict__ biasws) {
  int idx = blockIdx.x * 256 + threadIdx.x;  // 0 .. 1048576
  int h = idx >> 16;
  int rem = idx & 65535;
  int rb = rem >> 12;
  int ct = (rem >> 8) & 15;
  int L = (rem >> 2) & 63;
  int r = idx & 3;
  int row = rb * 16 + (L >> 4) * 4 + r;
  int col = ct * 16 + (L & 15);
  biasws[idx] = table[rel[row * 256 + col] * 16 + h];
}

// ---------------------------------------------------------------------------
// 256x256-tile 8-phase GEMM core, ROLLED K-loop (I-cache friendly).
// 8 waves (2M x 4N), per-wave 128x64 output = acc[8][4]. LDS 128 KiB
// (A,B K-tiles double-buffered, BK=64). XOR swizzle slot^=row&7 on
// pre-swizzled global source + ds_read address. Counted vmcnt(4) gates;
// vmcnt(0) only at the tail-group mid-gate. One output tile per block.
// ---------------------------------------------------------------------------
#define PH_MID()                                          \
  do {                                                    \
    __builtin_amdgcn_s_barrier();                         \
    asm volatile("s_waitcnt lgkmcnt(0)" ::: "memory");    \
    __builtin_amdgcn_sched_barrier(0);                    \
    __builtin_amdgcn_s_setprio(1);                        \
  } while (0)

#define PH_END()                                          \
  do {                                                    \
    __builtin_amdgcn_s_setprio(0);                        \
    __builtin_amdgcn_s_barrier();                         \
    __builtin_amdgcn_sched_barrier(0);                    \
  } while (0)

#define GATE4()                                           \
  do {                                                    \
    __builtin_amdgcn_s_setprio(0);                        \
    asm volatile("s_waitcnt vmcnt(4)" ::: "memory");      \
    __builtin_amdgcn_s_barrier();                         \
    __builtin_amdgcn_sched_barrier(0);                    \
  } while (0)

#define GATE0()                                           \
  do {                                                    \
    __builtin_amdgcn_s_setprio(0);                        \
    asm volatile("s_waitcnt vmcnt(0)" ::: "memory");      \
    __builtin_amdgcn_s_barrier();                         \
    __builtin_amdgcn_sched_barrier(0);                    \
  } while (0)

// stage rows [c*64, c*64+128) of one K-tile: src is per-thread swizzled
// global base of that tile, dst is per-thread LDS base of the buffer.
#define STG2(src, dst, c)                                                        \
  do {                                                                           \
    load_lds16((src) + (c)*32768, (dst) + (c)*4096);                             \
    load_lds16((src) + ((c) + 1) * 32768, (dst) + ((c) + 1) * 4096);             \
  } while (0)

#define RDA(dst, buf, ibase)                                                     \
  _Pragma("unroll") for (int i = 0; i < 4; ++i) {                                \
    dst[i][0] = *(const bf16x8*)&As[(buf)*16384 + a0 + ((ibase) + i) * 1024];    \
    dst[i][1] = *(const bf16x8*)&As[(buf)*16384 + a1 + ((ibase) + i) * 1024];    \
  }
#define RDB(dst, buf, jbase)                                                     \
  _Pragma("unroll") for (int j = 0; j < 2; ++j) {                                \
    dst[j][0] = *(const bf16x8*)&Bs[(buf)*16384 + b0 + ((jbase) + j) * 1024];    \
    dst[j][1] = *(const bf16x8*)&Bs[(buf)*16384 + b1 + ((jbase) + j) * 1024];    \
  }

#define MFQ(Af, Bf, I0, J0)                                                      \
  _Pragma("unroll") for (int i = 0; i < 4; ++i) _Pragma("unroll")                \
      for (int j = 0; j < 2; ++j) {                                              \
    acc[(I0) + i][(J0) + j] =                                                    \
        MFMA_16x16x32(Af[i][0], Bf[j][0], acc[(I0) + i][(J0) + j]);              \
    acc[(I0) + i][(J0) + j] =                                                    \
        MFMA_16x16x32(Af[i][1], Bf[j][1], acc[(I0) + i][(J0) + j]);              \
  }

// common per-thread geometry (names used by the macros)
#define GEMM_SETUP(Ap, Wp)                                                       \
  __shared__ bf16_t As[2 * 16384];                                               \
  __shared__ bf16_t Bs[2 * 16384];                                               \
  const int t = threadIdx.x;                                                     \
  const int w = t >> 6, L = t & 63;                                              \
  const int wm = w >> 2, wn = w & 3;                                             \
  const int lrow = L & 15, lq = L >> 4;                                          \
  const int srow = t >> 3;                                                       \
  const int sslot = (t & 7) ^ (srow & 7);                                        \
  const bf16_t* ga = (Ap) + (size_t)(m0 + srow) * 512 + sslot * 8;               \
  const bf16_t* gb = (Wp) + (size_t)(n0 + srow) * 512 + sslot * 8;               \
  bf16_t* la = As + t * 8;                                                       \
  bf16_t* lb = Bs + t * 8;                                                       \
  const int m8 = (lrow & 7) * 8;                                                 \
  const int a0 = (wm * 128 + lrow) * 64 + ((lq * 8) ^ m8);                       \
  const int a1 = (wm * 128 + lrow) * 64 + ((32 + lq * 8) ^ m8);                  \
  const int b0 = (wn * 64 + lrow) * 64 + ((lq * 8) ^ m8);                        \
  const int b1 = (wn * 64 + lrow) * 64 + ((32 + lq * 8) ^ m8);

// prologue: A0->buf0, B0->buf0, A1->buf1; gate to 8 landed (A1 in flight)
#define PROLOGUE()                                                               \
  STG2(ga, la, 0); STG2(ga, la, 2);                                              \
  STG2(gb, lb, 0); STG2(gb, lb, 2);                                              \
  STG2(ga + 64, la + 16384, 0); STG2(ga + 64, la + 16384, 2);                    \
  asm volatile("s_waitcnt vmcnt(4)" ::: "memory");                               \
  __builtin_amdgcn_s_barrier();                                                  \
  __builtin_amdgcn_sched_barrier(0);

// rolled K-loop: 3 steady groups (uniform staging) + tail group.
// steady group G: buf0 = tile 2G, buf1 = tile 2G+1; stages B(2G+1)->buf1,
// A(2G+2)->buf0, B(2G+2)->buf0, A(2G+3)->buf1. gA/gB advance 128 elems/group.
#define GEMM_LOOP()                                                              \
  {                                                                              \
    const bf16_t* gA = ga + 128; /* A(2) */                                      \
    const bf16_t* gB = gb + 64;  /* B(1) */                                      \
    _Pragma("unroll 1") for (int G = 0; G < 3; ++G) {                            \
      {                                                                          \
        bf16x8 fal[4][2], fbl[2][2], fah[4][2], fbh[2][2];                       \
        RDA(fal, 0, 0); RDB(fbl, 0, 0);                                          \
        STG2(gB, lb + 16384, 0);                                                 \
        PH_MID(); MFQ(fal, fbl, 0, 0); PH_END();                                 \
        RDA(fah, 0, 4);                                                          \
        STG2(gB, lb + 16384, 2);                                                 \
        PH_MID(); MFQ(fah, fbl, 4, 0); PH_END();                                 \
        RDB(fbh, 0, 2);                                                          \
        STG2(gA, la, 0);                                                         \
        PH_MID(); MFQ(fah, fbh, 4, 2); PH_END();                                 \
        STG2(gA, la, 2);                                                         \
        PH_MID(); MFQ(fal, fbh, 0, 2); GATE4();                                  \
      }                                                                          \
      {                                                                          \
        bf16x8 fal[4][2], fbl[2][2], fah[4][2], fbh[2][2];                       \
        RDA(fal, 1, 0); RDB(fbl, 1, 0);                                          \
        STG2(gB + 64, lb, 0);                                                    \
        PH_MID(); MFQ(fal, fbl, 0, 0); PH_END();                                 \
        RDA(fah, 1, 4);                                                          \
        STG2(gB + 64, lb, 2);                                                    \
        PH_MID(); MFQ(fah, fbl, 4, 0); PH_END();                                 \
        RDB(fbh, 1, 2);                                                          \
        STG2(gA + 64, la + 16384, 0);                                            \
        PH_MID(); MFQ(fah, fbh, 4, 2); PH_END();                                 \
        STG2(gA + 64, la + 16384, 2);                                            \
        PH_MID(); MFQ(fal, fbh, 0, 2); GATE4();                                  \
      }                                                                          \
      gA += 128; gB += 128;                                                      \
    }                                                                            \
    { /* tail group: tiles 6 (buf0) and 7 (buf1); stage only B7 */               \
      {                                                                          \
        bf16x8 fal[4][2], fbl[2][2], fah[4][2], fbh[2][2];                       \
        RDA(fal, 0, 0); RDB(fbl, 0, 0);                                          \
        STG2(gB, lb + 16384, 0);                                                 \
        PH_MID(); MFQ(fal, fbl, 0, 0); PH_END();                                 \
        RDA(fah, 0, 4);                                                          \
        STG2(gB, lb + 16384, 2);                                                 \
        PH_MID(); MFQ(fah, fbl, 4, 0); PH_END();                                 \
        RDB(fbh, 0, 2);                                                          \
        PH_MID(); MFQ(fah, fbh, 4, 2); PH_END();                                 \
        PH_MID(); MFQ(fal, fbh, 0, 2); GATE0();                                  \
      }                                                                          \
      {                                                                          \
        bf16x8 fal[4][2], fbl[2][2], fah[4][2], fbh[2][2];                       \
        RDA(fal, 1, 0); RDB(fbl, 1, 0);                                          \
        PH_MID(); MFQ(fal, fbl, 0, 0); PH_END();                                 \
        RDA(fah, 1, 4);                                                          \
        PH_MID(); MFQ(fah, fbl, 4, 0); PH_END();                                 \
        RDB(fbh, 1, 2);                                                          \
        PH_MID(); MFQ(fah, fbh, 4, 2); PH_END();                                 \
        PH_MID(); MFQ(fal, fbh, 0, 2);                                           \
        __builtin_amdgcn_s_setprio(0);                                           \
        __builtin_amdgcn_sched_barrier(0);                                       \
      }                                                                          \
    }                                                                            \
  }

// ---------------------------------------------------------------------------
// QKV GEMM: 768 blocks (r1 mapping: 6 nt of one mt consecutive on one XCD;
// FETCH ~37MB verified). One 256x256 tile per block, rolled 8-K-tile loop.
// ---------------------------------------------------------------------------
__global__ __launch_bounds__(512, 2) void qkv_gemm256_k(
    const bf16_t* __restrict__ A, const bf16_t* __restrict__ W,
    const float* __restrict__ Bvec,
    bf16_t* __restrict__ qws, bf16_t* __restrict__ kws, bf16_t* __restrict__ vws) {
  const int id = blockIdx.x;                  // 0..767
  const int wg = (id & 7) * 96 + (id >> 3);   // bijective XCD swizzle
  const int mt = wg / 6, nt = wg % 6;
  const int m0 = mt * 256, n0 = nt * 256;

  GEMM_SETUP(A, W);

  // bias folded into accumulator init
  f32x4 acc[8][4];
#pragma unroll
  for (int jj = 0; jj < 4; ++jj) {
    float bv = Bvec[n0 + wn * 64 + jj * 16 + lrow];
#pragma unroll
    for (int i = 0; i < 8; ++i) acc[i][jj] = (f32x4){bv, bv, bv, bv};
  }

  PROLOGUE();
  GEMM_LOOP();

  const int col0 = n0 + wn * 64;              // 64-aligned -> s uniform per wave
  const int s = col0 >> 9;
  bf16_t* dst = (s == 0) ? qws : (s == 1) ? kws : vws;
  const float mul = (s == 0) ? 0.17677669529663687f : 1.0f;  // 1/sqrt(32) on q
#pragma unroll
  for (int jj = 0; jj < 4; ++jj) {
    int o = col0 + jj * 16 + lrow;
    int rem = o & 511;
    int hh = rem >> 5, d = rem & 31;
#pragma unroll
    for (int i = 0; i < 8; ++i) {
#pragma unroll
      for (int r = 0; r < 4; ++r) {
        int m = m0 + wm * 128 + i * 16 + lq * 4 + r;
        int b = m >> 8, n = m & 255;
        dst[(size_t)(((b * 16 + hh) * 256 + n) << 5) + d] =
            (bf16_t)(acc[i][jj][r] * mul);
      }
    }
  }
}

// ---------------------------------------------------------------------------
// Proj GEMM 256x256: 128 mt x 2 nt = 256 blocks, rolled loop.
// ---------------------------------------------------------------------------
__global__ __launch_bounds__(512, 2) void proj_gemm256_k(
    const bf16_t* __restrict__ A, const bf16_t* __restrict__ W,
    const float* __restrict__ Bvec, float* __restrict__ out) {
  const int id = blockIdx.x;                  // 0..255
  const int lin = (id & 7) * 32 + (id >> 3);
  const int mt = lin >> 1, nt = lin & 1;
  const int m0 = mt * 256, n0 = nt * 256;

  GEMM_SETUP(A, W);

  f32x4 acc[8][4];
#pragma unroll
  for (int jj = 0; jj < 4; ++jj) {
    float bv = Bvec[n0 + wn * 64 + jj * 16 + lrow];
#pragma unroll
    for (int i = 0; i < 8; ++i) acc[i][jj] = (f32x4){bv, bv, bv, bv};
  }

  PROLOGUE();
  GEMM_LOOP();

#pragma unroll
  for (int jj = 0; jj < 4; ++jj) {
    int o = n0 + wn * 64 + jj * 16 + lrow;
#pragma unroll
    for (int i = 0; i < 8; ++i) {
#pragma unroll
      for (int r = 0; r < 4; ++r) {
        int m = m0 + wm * 128 + i * 16 + lq * 4 + r;
        out[(size_t)m * 512 + o] = acc[i][jj][r];
      }
    }
  }
}

// ---------------------------------------------------------------------------
// Attention: one block per (b, h, 64-row strip), XCD-swizzled (strips of one
// (b,h) consecutive on same XCD; each XCD serves 2 h values -> bias L2-hot).
// ---------------------------------------------------------------------------
__global__ __launch_bounds__(256) void attn_k(
    const bf16_t* __restrict__ qws, const bf16_t* __restrict__ kws,
    const bf16_t* __restrict__ vws, const float* __restrict__ biasws,
    bf16_t* __restrict__ aows) {
  __shared__ __align__(16) char smem[33792 + 16896];
  bf16_t* Ps = (bf16_t*)smem;            // 4 waves x [16][264]
  bf16_t* Vs = (bf16_t*)(smem + 33792);  // [32][264] transposed V

  const int id = blockIdx.x;             // 0..8191
  const int xcd = id & 7;
  const int jj = id >> 3;                // 0..1023
  const int bh = (jj >> 2) * 8 + xcd;    // 0..2047
  const int strip = jj & 3;
  const int h = bh & 15, b = bh >> 4;

  const int t = threadIdx.x;
  const int w = t >> 6, L = t & 63;
  const int lrow = L & 15, lq = L >> 4;

  const bf16_t* kbase = kws + (size_t)bh * 8192;
  const bf16_t* vbase = vws + (size_t)bh * 8192;
#pragma unroll
  for (int c = 0; c < 4; c++) {
    bf16x8 vv = *(const bf16x8*)(vbase + t * 32 + c * 8);
#pragma unroll
    for (int j = 0; j < 8; j++) Vs[(c * 8 + j) * 264 + t] = vv[j];
  }

  const bf16_t* qbase = qws + (size_t)bh * 8192 + (strip * 64 + w * 16) * 32;
  bf16x8 qf = *(const bf16x8*)(qbase + lrow * 32 + lq * 8);
  bf16x8 kf[16];
#pragma unroll
  for (int ct = 0; ct < 16; ct++)
    kf[ct] = *(const bf16x8*)(kbase + (ct * 16 + lrow) * 32 + lq * 8);

  const float* bb = biasws + h * 65536 + (strip * 4 + w) * 4096;
  f32x4 S[16];
#pragma unroll
  for (int ct = 0; ct < 16; ct++) {
    f32x4 bi = *(const f32x4*)(bb + ct * 256 + L * 4);
    S[ct] = MFMA_16x16x32(qf, kf[ct], bi);
  }

  float sm[4] = {0.f, 0.f, 0.f, 0.f};
#pragma unroll
  for (int ct = 0; ct < 16; ct++)
#pragma unroll
    for (int r = 0; r < 4; r++) {
      float e = __expf(S[ct][r]);
      S[ct][r] = e;
      sm[r] += e;
    }
#pragma unroll
  for (int r = 0; r < 4; r++)
#pragma unroll
    for (int msk = 1; msk < 16; msk <<= 1)
      sm[r] += __shfl_xor(sm[r], msk, 64);
  float inv[4];
#pragma unroll
  for (int r = 0; r < 4; r++) inv[r] = 1.0f / sm[r];

  bf16_t* Pw = Ps + w * 4224;
#pragma unroll
  for (int ct = 0; ct < 16; ct++)
#pragma unroll
    for (int r = 0; r < 4; r++)
      Pw[(lq * 4 + r) * 264 + ct * 16 + lrow] = (bf16_t)S[ct][r];

  __syncthreads();  // Vs writes visible to all waves

  f32x4 O0 = {}, O1 = {};
#pragma unroll
  for (int c = 0; c < 8; c++) {
    bf16x8 pf = *(const bf16x8*)&Pw[lrow * 264 + c * 32 + lq * 8];
    bf16x8 v0 = *(const bf16x8*)&Vs[lrow * 264 + c * 32 + lq * 8];
    bf16x8 v1 = *(const bf16x8*)&Vs[(16 + lrow) * 264 + c * 32 + lq * 8];
    O0 = MFMA_16x16x32(pf, v0, O0);
    O1 = MFMA_16x16x32(pf, v1, O1);
  }
  bf16_t* obase = aows + (size_t)(b * 256 + strip * 64 + w * 16) * 512 + h * 32;
#pragma unroll
  for (int r = 0; r < 4; r++) {
    int rl = lq * 4 + r;
    obase[rl * 512 + lrow] = (bf16_t)(O0[r] * inv[r]);
    obase[rl * 512 + 16 + lrow] = (bf16_t)(O1[r] * inv[r]);
  }
}

// ---------------------------------------------------------------------------
extern "C" void kernel_launch(void* const* d_in, const int* in_sizes, int n_in,
                              void* d_out, int out_size, void* d_ws, size_t ws_size,
                              hipStream_t stream) {
  (void)in_sizes; (void)n_in; (void)out_size; (void)ws_size;
  const float* x      = (const float*)d_in[0];
  const float* qkv_w  = (const float*)d_in[1];
  const float* qkv_b  = (const float*)d_in[2];
  const float* proj_w = (const float*)d_in[3];
  const float* proj_b = (const float*)d_in[4];
  const float* table  = (const float*)d_in[5];
  const int*   rel    = (const int*)d_in[6];

  const size_t QKV_ELEMS = 16777216;  // 128*16*256*32
  bf16_t* qws     = (bf16_t*)d_ws;
  bf16_t* kws     = qws + QKV_ELEMS;
  bf16_t* vws     = kws + QKV_ELEMS;
  float*  biasws  = (float*)(vws + QKV_ELEMS);
  bf16_t* wqkvbf  = (bf16_t*)(biasws + 1048576);
  bf16_t* wprojbf = wqkvbf + 786432;
  bf16_t* xbf     = wprojbf + 262144;  // aliased with aows (liveness disjoint)
  bf16_t* aows    = xbf;
  float*  out     = (float*)d_out;

  convert_k<<<8704, 256, 0, stream>>>(x, qkv_w, proj_w, xbf, wqkvbf, wprojbf);
  bias_gather_k<<<4096, 256, 0, stream>>>(table, rel, biasws);
  qkv_gemm256_k<<<768, 512, 0, stream>>>(xbf, wqkvbf, qkv_b, qws, kws, vws);
  attn_k<<<8192, 256, 0, stream>>>(qws, kws, vws, biasws, aows);
  proj_gemm256_k<<<256, 512, 0, stream>>>(aows, wprojbf, proj_b, out);
}